// Round 2
// baseline (95.898 us; speedup 1.0000x reference)
//
#include <hip/hip_runtime.h>

namespace {
constexpr int Bn = 8, LQ = 512, LK = 512, Dn = 64;
constexpr int T = 512, QT = 8, KT = 256, NT = LK / KT;
constexpr float C2 = 2.8853900817779268f; // 2*log2(e)

// score(b,q,k) = sum_d tanh(q_d+k_d) = 64 - 2*sum_d rcp(e^{2q_d} e^{2k_d} + 1)
// p = e^{score-64} = exp2(-C2 * acc); acc in (0,64) -> no overflow, exact softmax.
__global__ __launch_bounds__(T, 4)
void addattn(const float* __restrict__ Q, const float* __restrict__ K,
             const float* __restrict__ V, float* __restrict__ O)
{
  __shared__ __align__(16) float ek[KT][Dn + 1];   // e^{2k}; pad 65 -> 2-way reads (free)
  __shared__ __align__(16) float eqs[QT][Dn];      // e^{2q}; wave-uniform b128 reads
  __shared__ __align__(16) float pl[QT][KT + 4];   // p tile
  __shared__ float lsum[QT];

  const int t  = threadIdx.x;
  const int bb = blockIdx.x >> 6;
  const int q0 = (blockIdx.x & 63) * QT;

  // ---- one-time: eq = exp(2q) for the 8 q-rows
  if (t < 128) {
    const int r = t >> 4, d4 = t & 15;
    float4 qv = *(const float4*)(Q + ((bb * LQ + q0 + r) * Dn) + d4 * 4);
    float4 e;
    e.x = __builtin_amdgcn_exp2f(qv.x * C2);
    e.y = __builtin_amdgcn_exp2f(qv.y * C2);
    e.z = __builtin_amdgcn_exp2f(qv.z * C2);
    e.w = __builtin_amdgcn_exp2f(qv.w * C2);
    *(float4*)&eqs[r][d4 * 4] = e;
  }
  if (t < QT) lsum[t] = 0.f;

  // ---- K-tile staging: loads into regs early, exp+LDS-write late
  const int sk_ = t >> 4, sd_ = t & 15;
  float4 kv[8];
  const float* kbase = K + (bb * LK) * Dn + sd_ * 4;

  #pragma unroll
  for (int p = 0; p < 8; ++p)               // prologue: tile 0 loads
    kv[p] = *(const float4*)(kbase + (p * 32 + sk_) * Dn);
  #pragma unroll
  for (int p = 0; p < 8; ++p) {             // tile 0 exp + write
    const int row = p * 32 + sk_;
    ek[row][sd_ * 4 + 0] = __builtin_amdgcn_exp2f(kv[p].x * C2);
    ek[row][sd_ * 4 + 1] = __builtin_amdgcn_exp2f(kv[p].y * C2);
    ek[row][sd_ * 4 + 2] = __builtin_amdgcn_exp2f(kv[p].z * C2);
    ek[row][sd_ * 4 + 3] = __builtin_amdgcn_exp2f(kv[p].w * C2);
  }
  __syncthreads();                          // ek[t0], eqs, lsum ready

  // score-phase mapping: thread owns 4 q-rows x 1 k
  const int kk = t & 255;
  const int qb = (t >> 8) * 4;              // 0 or 4
  // PV mapping: thread owns 2 q-rows x 4 d x 32 k
  const int dq  = t & 15;
  const int rg  = (t >> 4) & 3;             // rows 2rg, 2rg+1
  const int seg = t >> 6;                   // k sub-range of 32 (wave-uniform)
  float ac00 = 0.f, ac01 = 0.f, ac02 = 0.f, ac03 = 0.f;
  float ac10 = 0.f, ac11 = 0.f, ac12 = 0.f, ac13 = 0.f;

  for (int tile = 0; tile < NT; ++tile) {
    const int k0 = tile * KT;

    if (tile + 1 < NT) {                    // prefetch next tile's K (hides under scores)
      #pragma unroll
      for (int p = 0; p < 8; ++p)
        kv[p] = *(const float4*)(kbase + (k0 + KT + p * 32 + sk_) * Dn);
    }

    // ---- scores: 16 rcp per 4 ek loads; eq reads wave-uniform
    {
      float a0 = 0.f, a1 = 0.f, a2 = 0.f, a3 = 0.f;
      #pragma unroll
      for (int d4 = 0; d4 < 16; ++d4) {
        const float4 e0 = *(const float4*)&eqs[qb + 0][d4 * 4];
        const float4 e1 = *(const float4*)&eqs[qb + 1][d4 * 4];
        const float4 e2 = *(const float4*)&eqs[qb + 2][d4 * 4];
        const float4 e3 = *(const float4*)&eqs[qb + 3][d4 * 4];
        const float x0 = ek[kk][d4 * 4 + 0];
        const float x1 = ek[kk][d4 * 4 + 1];
        const float x2 = ek[kk][d4 * 4 + 2];
        const float x3 = ek[kk][d4 * 4 + 3];
        a0 += __builtin_amdgcn_rcpf(fmaf(e0.x, x0, 1.f));
        a1 += __builtin_amdgcn_rcpf(fmaf(e1.x, x0, 1.f));
        a2 += __builtin_amdgcn_rcpf(fmaf(e2.x, x0, 1.f));
        a3 += __builtin_amdgcn_rcpf(fmaf(e3.x, x0, 1.f));
        a0 += __builtin_amdgcn_rcpf(fmaf(e0.y, x1, 1.f));
        a1 += __builtin_amdgcn_rcpf(fmaf(e1.y, x1, 1.f));
        a2 += __builtin_amdgcn_rcpf(fmaf(e2.y, x1, 1.f));
        a3 += __builtin_amdgcn_rcpf(fmaf(e3.y, x1, 1.f));
        a0 += __builtin_amdgcn_rcpf(fmaf(e0.z, x2, 1.f));
        a1 += __builtin_amdgcn_rcpf(fmaf(e1.z, x2, 1.f));
        a2 += __builtin_amdgcn_rcpf(fmaf(e2.z, x2, 1.f));
        a3 += __builtin_amdgcn_rcpf(fmaf(e3.z, x2, 1.f));
        a0 += __builtin_amdgcn_rcpf(fmaf(e0.w, x3, 1.f));
        a1 += __builtin_amdgcn_rcpf(fmaf(e1.w, x3, 1.f));
        a2 += __builtin_amdgcn_rcpf(fmaf(e2.w, x3, 1.f));
        a3 += __builtin_amdgcn_rcpf(fmaf(e3.w, x3, 1.f));
      }
      const float p0 = __builtin_amdgcn_exp2f(-C2 * a0);
      const float p1 = __builtin_amdgcn_exp2f(-C2 * a1);
      const float p2 = __builtin_amdgcn_exp2f(-C2 * a2);
      const float p3 = __builtin_amdgcn_exp2f(-C2 * a3);
      pl[qb + 0][kk] = p0;
      pl[qb + 1][kk] = p1;
      pl[qb + 2][kk] = p2;
      pl[qb + 3][kk] = p3;

      // row sums: in-wave 64-lane reduce (each wave covers 64 distinct k)
      float s0 = p0, s1 = p1, s2 = p2, s3 = p3;
      #pragma unroll
      for (int m = 1; m < 64; m <<= 1) {
        s0 += __shfl_xor(s0, m);
        s1 += __shfl_xor(s1, m);
        s2 += __shfl_xor(s2, m);
        s3 += __shfl_xor(s3, m);
      }
      if ((t & 63) == 0) {
        atomicAdd(&lsum[qb + 0], s0);
        atomicAdd(&lsum[qb + 1], s1);
        atomicAdd(&lsum[qb + 2], s2);
        atomicAdd(&lsum[qb + 3], s3);
      }
    }
    __syncthreads();                        // pl ready; ek free to overwrite

    // ---- PV accumulate (V from global; L1/L2 resident)
    {
      const float* vb   = V + ((bb * LK + k0 + seg * 32) * Dn) + dq * 4;
      const float* pr0  = &pl[2 * rg + 0][seg * 32];
      const float* pr1  = &pl[2 * rg + 1][seg * 32];
      #pragma unroll 8
      for (int j = 0; j < 32; ++j) {
        float4 v4 = *(const float4*)(vb + j * Dn);
        float pa = pr0[j], pb = pr1[j];
        ac00 = fmaf(pa, v4.x, ac00);
        ac01 = fmaf(pa, v4.y, ac01);
        ac02 = fmaf(pa, v4.z, ac02);
        ac03 = fmaf(pa, v4.w, ac03);
        ac10 = fmaf(pb, v4.x, ac10);
        ac11 = fmaf(pb, v4.y, ac11);
        ac12 = fmaf(pb, v4.z, ac12);
        ac13 = fmaf(pb, v4.w, ac13);
      }
    }

    if (tile + 1 < NT) {                    // next tile exp + LDS write (ek free after barrier B)
      #pragma unroll
      for (int p = 0; p < 8; ++p) {
        const int row = p * 32 + sk_;
        ek[row][sd_ * 4 + 0] = __builtin_amdgcn_exp2f(kv[p].x * C2);
        ek[row][sd_ * 4 + 1] = __builtin_amdgcn_exp2f(kv[p].y * C2);
        ek[row][sd_ * 4 + 2] = __builtin_amdgcn_exp2f(kv[p].z * C2);
        ek[row][sd_ * 4 + 3] = __builtin_amdgcn_exp2f(kv[p].w * C2);
      }
    }
    __syncthreads();                        // ek[t+1] ready / pl free
  }

  // ---- epilogue: reduce the 8 k-segments; reuse ek region as scratch
  float* scr = &ek[0][0];                   // [8 segs][8 rows][64 d]
  *(float4*)(scr + ((seg * 8 + 2 * rg + 0) * 64) + dq * 4) =
      make_float4(ac00, ac01, ac02, ac03);
  *(float4*)(scr + ((seg * 8 + 2 * rg + 1) * 64) + dq * 4) =
      make_float4(ac10, ac11, ac12, ac13);
  __syncthreads();
  if (t < 128) {
    const int row = t >> 4, d4 = t & 15;
    float4 o = make_float4(0.f, 0.f, 0.f, 0.f);
    #pragma unroll
    for (int s = 0; s < 8; ++s) {
      float4 c = *(const float4*)(scr + ((s * 8 + row) * 64) + d4 * 4);
      o.x += c.x; o.y += c.y; o.z += c.z; o.w += c.w;
    }
    const float inv = 1.0f / lsum[row];
    o.x *= inv; o.y *= inv; o.z *= inv; o.w *= inv;
    *(float4*)(O + ((bb * LQ + q0 + row) * Dn) + d4 * 4) = o;
  }
}
} // namespace

extern "C" void kernel_launch(void* const* d_in, const int* in_sizes, int n_in,
                              void* d_out, int out_size, void* d_ws, size_t ws_size,
                              hipStream_t stream) {
  (void)in_sizes; (void)n_in; (void)d_ws; (void)ws_size; (void)out_size;
  const float* Q = (const float*)d_in[0];
  const float* K = (const float*)d_in[1];
  const float* V = (const float*)d_in[2];
  float* O = (float*)d_out;
  addattn<<<dim3(Bn * (LQ / QT)), dim3(T), 0, stream>>>(Q, K, V, O);
}

// Round 3
// 85.008 us; speedup vs baseline: 1.1281x; 1.1281x over previous
//
#include <hip/hip_runtime.h>

namespace {
constexpr int Bn = 8, LQ = 512, LK = 512, Dn = 64;
constexpr int T = 512, QT = 8, KT = 128, NT = LK / KT;
constexpr float C2 = 2.8853900817779268f; // 2*log2(e)

// score(b,q,k) = sum_d tanh(q_d+k_d) = 64 - 2*sum_d rcp(e^{2q_d} e^{2k_d} + 1)
// p = e^{score-64} = exp2(-C2 * acc); acc in (0,64) -> no overflow, exact softmax.
__global__ __launch_bounds__(T, 4)
void addattn(const float* __restrict__ Q, const float* __restrict__ K,
             const float* __restrict__ V, float* __restrict__ O)
{
  __shared__ __align__(16) float ek[KT][66];       // e^{2k}; 66 -> 8B-aligned b64, 2-way free
  __shared__ __align__(16) float eqs[QT][Dn];      // e^{2q}; wave-uniform b128 reads
  __shared__ __align__(16) float pl[QT][KT + 4];   // p tile
  __shared__ float lsum[QT];

  const int t  = threadIdx.x;
  const int bb = blockIdx.x >> 6;
  const int q0 = (blockIdx.x & 63) * QT;

  // staging map (K): thread covers rows p*32+sk_, col quad sd_
  const int sk_ = t >> 4, sd_ = t & 15;
  // score map: 1 k-col, 2 q-rows
  const int kk = t & 127;
  const int qg = (t >> 7) * 2;
  // PV map: 4 d, 2 q-rows, 16 k
  const int dq  = t & 15;
  const int rg  = (t >> 4) & 3;
  const int seg = t >> 6;

  const float* kbase = K + (bb * LK) * Dn + sd_ * 4;

  // ---- prologue: eq = exp(2q); K tile 0 staged
  if (t < 128) {
    const int r = t >> 4, d4 = t & 15;
    float4 qv = *(const float4*)(Q + ((bb * LQ + q0 + r) * Dn) + d4 * 4);
    float4 e;
    e.x = __builtin_amdgcn_exp2f(qv.x * C2);
    e.y = __builtin_amdgcn_exp2f(qv.y * C2);
    e.z = __builtin_amdgcn_exp2f(qv.z * C2);
    e.w = __builtin_amdgcn_exp2f(qv.w * C2);
    *(float4*)&eqs[r][d4 * 4] = e;
  }
  if (t < QT) lsum[t] = 0.f;

  float4 kv[4];
  #pragma unroll
  for (int p = 0; p < 4; ++p)
    kv[p] = *(const float4*)(kbase + (p * 32 + sk_) * Dn);
  #pragma unroll
  for (int p = 0; p < 4; ++p) {
    const int row = p * 32 + sk_;
    ek[row][sd_ * 4 + 0] = __builtin_amdgcn_exp2f(kv[p].x * C2);
    ek[row][sd_ * 4 + 1] = __builtin_amdgcn_exp2f(kv[p].y * C2);
    ek[row][sd_ * 4 + 2] = __builtin_amdgcn_exp2f(kv[p].z * C2);
    ek[row][sd_ * 4 + 3] = __builtin_amdgcn_exp2f(kv[p].w * C2);
  }
  __syncthreads();

  float ac00 = 0.f, ac01 = 0.f, ac02 = 0.f, ac03 = 0.f;
  float ac10 = 0.f, ac11 = 0.f, ac12 = 0.f, ac13 = 0.f;

  for (int tile = 0; tile < NT; ++tile) {
    const int k0 = tile * KT;

    // ---- issue THIS tile's V loads (consumed after barrier A; hidden by scores)
    float4 vv[16];
    {
      const float* vbase = V + ((bb * LK + k0 + seg * 16) * Dn) + dq * 4;
      #pragma unroll
      for (int j = 0; j < 16; ++j)
        vv[j] = *(const float4*)(vbase + j * Dn);
    }
    // ---- issue NEXT tile's K loads (consumed in staging; hidden by scores+PV)
    if (tile + 1 < NT) {
      #pragma unroll
      for (int p = 0; p < 4; ++p)
        kv[p] = *(const float4*)(kbase + (k0 + KT + p * 32 + sk_) * Dn);
    }

    // ---- scores: 2 q-rows x 1 k; 4 independent chains
    {
      float a0 = 0.f, b0 = 0.f, a1 = 0.f, b1 = 0.f;
      const float* ekr = &ek[kk][0];
      const float* eq0 = &eqs[qg + 0][0];
      const float* eq1 = &eqs[qg + 1][0];
      #pragma unroll
      for (int d4 = 0; d4 < 16; ++d4) {
        const float4 e0 = *(const float4*)(eq0 + d4 * 4);
        const float4 e1 = *(const float4*)(eq1 + d4 * 4);
        const float2 xA = *(const float2*)(ekr + d4 * 4);
        const float2 xB = *(const float2*)(ekr + d4 * 4 + 2);
        a0 += __builtin_amdgcn_rcpf(fmaf(e0.x, xA.x, 1.f));
        b0 += __builtin_amdgcn_rcpf(fmaf(e0.y, xA.y, 1.f));
        a0 += __builtin_amdgcn_rcpf(fmaf(e0.z, xB.x, 1.f));
        b0 += __builtin_amdgcn_rcpf(fmaf(e0.w, xB.y, 1.f));
        a1 += __builtin_amdgcn_rcpf(fmaf(e1.x, xA.x, 1.f));
        b1 += __builtin_amdgcn_rcpf(fmaf(e1.y, xA.y, 1.f));
        a1 += __builtin_amdgcn_rcpf(fmaf(e1.z, xB.x, 1.f));
        b1 += __builtin_amdgcn_rcpf(fmaf(e1.w, xB.y, 1.f));
      }
      const float p0 = __builtin_amdgcn_exp2f(-C2 * (a0 + b0));
      const float p1 = __builtin_amdgcn_exp2f(-C2 * (a1 + b1));
      pl[qg + 0][kk] = p0;
      pl[qg + 1][kk] = p1;

      float s0 = p0, s1 = p1;
      #pragma unroll
      for (int m = 1; m < 64; m <<= 1) {
        s0 += __shfl_xor(s0, m);
        s1 += __shfl_xor(s1, m);
      }
      if ((t & 63) == 0) {
        atomicAdd(&lsum[qg + 0], s0);
        atomicAdd(&lsum[qg + 1], s1);
      }
    }
    __syncthreads();                        // barrier A: pl ready, ek free

    // ---- PV from registers (V latency long gone) + pl broadcast reads
    {
      const float* pr0 = &pl[2 * rg + 0][seg * 16];
      const float* pr1 = &pl[2 * rg + 1][seg * 16];
      #pragma unroll
      for (int j = 0; j < 16; ++j) {
        const float pa = pr0[j], pb = pr1[j];
        ac00 = fmaf(pa, vv[j].x, ac00);
        ac01 = fmaf(pa, vv[j].y, ac01);
        ac02 = fmaf(pa, vv[j].z, ac02);
        ac03 = fmaf(pa, vv[j].w, ac03);
        ac10 = fmaf(pb, vv[j].x, ac10);
        ac11 = fmaf(pb, vv[j].y, ac11);
        ac12 = fmaf(pb, vv[j].z, ac12);
        ac13 = fmaf(pb, vv[j].w, ac13);
      }
    }

    // ---- stage next K tile into ek (free since barrier A)
    if (tile + 1 < NT) {
      #pragma unroll
      for (int p = 0; p < 4; ++p) {
        const int row = p * 32 + sk_;
        ek[row][sd_ * 4 + 0] = __builtin_amdgcn_exp2f(kv[p].x * C2);
        ek[row][sd_ * 4 + 1] = __builtin_amdgcn_exp2f(kv[p].y * C2);
        ek[row][sd_ * 4 + 2] = __builtin_amdgcn_exp2f(kv[p].z * C2);
        ek[row][sd_ * 4 + 3] = __builtin_amdgcn_exp2f(kv[p].w * C2);
      }
    }
    __syncthreads();                        // barrier B: ek[t+1] ready, pl free
  }

  // ---- epilogue: reduce 8 k-segments via ek-region scratch
  float* scr = &ek[0][0];                   // [8 segs][8 rows][64 d] = 16KB
  *(float4*)(scr + ((seg * 8 + 2 * rg + 0) * 64) + dq * 4) =
      make_float4(ac00, ac01, ac02, ac03);
  *(float4*)(scr + ((seg * 8 + 2 * rg + 1) * 64) + dq * 4) =
      make_float4(ac10, ac11, ac12, ac13);
  __syncthreads();
  if (t < 128) {
    const int row = t >> 4, d4 = t & 15;
    float4 o = make_float4(0.f, 0.f, 0.f, 0.f);
    #pragma unroll
    for (int s = 0; s < 8; ++s) {
      float4 c = *(const float4*)(scr + ((s * 8 + row) * 64) + d4 * 4);
      o.x += c.x; o.y += c.y; o.z += c.z; o.w += c.w;
    }
    const float inv = 1.0f / lsum[row];
    o.x *= inv; o.y *= inv; o.z *= inv; o.w *= inv;
    *(float4*)(O + ((bb * LQ + q0 + row) * Dn) + d4 * 4) = o;
  }
}
} // namespace

extern "C" void kernel_launch(void* const* d_in, const int* in_sizes, int n_in,
                              void* d_out, int out_size, void* d_ws, size_t ws_size,
                              hipStream_t stream) {
  (void)in_sizes; (void)n_in; (void)d_ws; (void)ws_size; (void)out_size;
  const float* Q = (const float*)d_in[0];
  const float* K = (const float*)d_in[1];
  const float* V = (const float*)d_in[2];
  float* O = (float*)d_out;
  addattn<<<dim3(Bn * (LQ / QT)), dim3(T), 0, stream>>>(Q, K, V, O);
}

// Round 5
// 80.989 us; speedup vs baseline: 1.1841x; 1.0496x over previous
//
#include <hip/hip_runtime.h>

namespace {
constexpr int Bn = 8, LQ = 512, LK = 512, Dn = 64;
constexpr int T = 512, QT = 8, KT = 64, NT = LK / KT;
constexpr float C2 = 2.8853900817779268f; // 2*log2(e)

// score(b,q,k) = sum_d tanh(q_d+k_d) = 64 - 2a, a = sum_d rcp(1 + e^{2q_d}e^{2k_d})
// p = e^{score-64} = exp2(-C2*a); a in (0,64) -> no overflow; softmax exact (scale cancels).
__device__ __forceinline__ void gload_lds16(const float* g, float* l) {
  __builtin_amdgcn_global_load_lds(
      (const __attribute__((address_space(1))) void*)g,
      (__attribute__((address_space(3))) void*)l, 16, 0, 0);
}

__global__ __launch_bounds__(T, 4)
void addattn(const float* __restrict__ Q, const float* __restrict__ K,
             const float* __restrict__ V, float* __restrict__ O)
{
  __shared__ __align__(16) float ekL[2][KT][68];  // e^{2k}, dbuf; stride 272B (16B mult)
  __shared__ __align__(16) float vL [2][KT][Dn];  // V, dbuf; linear for global_load_lds
  __shared__ __align__(16) float eqs[QT][Dn];     // e^{2q}; wave-uniform reads
  __shared__ __align__(16) float pL [QT][68];     // p row per wave (wave-private)
  __shared__ float lsum[QT];

  const int t    = threadIdx.x;
  const int w    = t >> 6;          // wave id == q-row (0..7)
  const int lane = t & 63;          // score: k within tile
  const int ks   = (t >> 4) & 3;    // PV: k-slice of 16
  const int dq   = t & 15;          // PV: d-quad
  const int krow = t >> 3;          // K staging: row 0..63
  const int kc8  = (t & 7) * 8;     // K staging: col base
  const int bb   = blockIdx.x >> 6;
  const int q0   = (blockIdx.x & 63) * QT;

  const float* Kt = K + (size_t)bb * LK * Dn;
  const float* Vt = V + (size_t)bb * LK * Dn;

  // ---- prologue: eq = exp(2q)
  if (t < 128) {
    const int r = t >> 4, d4 = t & 15;
    float4 qv = *(const float4*)(Q + (size_t)(bb * LQ + q0 + r) * Dn + d4 * 4);
    float4 e;
    e.x = __builtin_amdgcn_exp2f(qv.x * C2);
    e.y = __builtin_amdgcn_exp2f(qv.y * C2);
    e.z = __builtin_amdgcn_exp2f(qv.z * C2);
    e.w = __builtin_amdgcn_exp2f(qv.w * C2);
    *(float4*)&eqs[r][d4 * 4] = e;
  }
  // ---- V tile 0 -> vL[0] (async DMA, no VGPR round-trip)
  {
    const float* g = Vt + (size_t)(w * 8) * Dn + lane * 4;
    float* l = &vL[0][w * 8][0];
    gload_lds16(g, l);
    gload_lds16(g + 256, l + 256);
  }
  // ---- K tile 0 -> ekL[0]
  {
    float4 k0v = *(const float4*)(Kt + (size_t)krow * Dn + kc8);
    float4 k1v = *(const float4*)(Kt + (size_t)krow * Dn + kc8 + 4);
    float4 e0, e1;
    e0.x = __builtin_amdgcn_exp2f(k0v.x * C2);
    e0.y = __builtin_amdgcn_exp2f(k0v.y * C2);
    e0.z = __builtin_amdgcn_exp2f(k0v.z * C2);
    e0.w = __builtin_amdgcn_exp2f(k0v.w * C2);
    e1.x = __builtin_amdgcn_exp2f(k1v.x * C2);
    e1.y = __builtin_amdgcn_exp2f(k1v.y * C2);
    e1.z = __builtin_amdgcn_exp2f(k1v.z * C2);
    e1.w = __builtin_amdgcn_exp2f(k1v.w * C2);
    *(float4*)&ekL[0][krow][kc8]     = e0;
    *(float4*)&ekL[0][krow][kc8 + 4] = e1;
  }
  __syncthreads();   // vmcnt(0)+lgkmcnt(0) drain: tile 0 fully staged

  float  dsum = 0.f;                         // per-lane denom partial (row w)
  float4 acc  = make_float4(0.f, 0.f, 0.f, 0.f);  // PV partial (row w, slice ks)
  int buf = 0;

  for (int tile = 0; tile < NT; ++tile) {
    float4 kv0, kv1;
    const bool more = (tile + 1 < NT);
    if (more) {
      const int kb = (tile + 1) * KT;
      // next V tile -> back buffer (async; lands by next barrier, hidden under score+PV)
      const float* g = Vt + (size_t)(kb + w * 8) * Dn + lane * 4;
      float* l = &vL[buf ^ 1][w * 8][0];
      gload_lds16(g, l);
      gload_lds16(g + 256, l + 256);
      // next K tile -> regs (only 8 VGPR live across score)
      kv0 = *(const float4*)(Kt + (size_t)(kb + krow) * Dn + kc8);
      kv1 = *(const float4*)(Kt + (size_t)(kb + krow) * Dn + kc8 + 4);
    }

    // ---- score: wave w = q-row w, lane = k; 4 independent rcp chains
    {
      float a0 = 0.f, a1 = 0.f, a2 = 0.f, a3 = 0.f;
      const float* ekr = &ekL[buf][lane][0];
      const float* eqr = &eqs[w][0];
      #pragma unroll
      for (int d4 = 0; d4 < 16; ++d4) {
        const float4 e = *(const float4*)(eqr + d4 * 4);  // wave-uniform broadcast
        const float4 x = *(const float4*)(ekr + d4 * 4);  // lane-varying, b128 floor
        a0 += __builtin_amdgcn_rcpf(fmaf(e.x, x.x, 1.f));
        a1 += __builtin_amdgcn_rcpf(fmaf(e.y, x.y, 1.f));
        a2 += __builtin_amdgcn_rcpf(fmaf(e.z, x.z, 1.f));
        a3 += __builtin_amdgcn_rcpf(fmaf(e.w, x.w, 1.f));
      }
      const float p = __builtin_amdgcn_exp2f(-C2 * ((a0 + a1) + (a2 + a3)));
      dsum += p;
      pL[w][lane] = p;        // wave-private row: consumed below by same wave
    }

    // ---- PV: row w, k-slice ks (p via within-wave LDS, V from front buffer)
    {
      const float* vrow = &vL[buf][ks * 16][dq * 4];
      const float* prow = &pL[w][ks * 16];
      #pragma unroll
      for (int j = 0; j < 16; ++j) {
        const float4 v4 = *(const float4*)(vrow + j * Dn);
        const float  pw = prow[j];
        acc.x = fmaf(pw, v4.x, acc.x);
        acc.y = fmaf(pw, v4.y, acc.y);
        acc.z = fmaf(pw, v4.z, acc.z);
        acc.w = fmaf(pw, v4.w, acc.w);
      }
    }

    // ---- stage next K into back buffer (nobody reads it until after barrier)
    if (more) {
      float4 e0, e1;
      e0.x = __builtin_amdgcn_exp2f(kv0.x * C2);
      e0.y = __builtin_amdgcn_exp2f(kv0.y * C2);
      e0.z = __builtin_amdgcn_exp2f(kv0.z * C2);
      e0.w = __builtin_amdgcn_exp2f(kv0.w * C2);
      e1.x = __builtin_amdgcn_exp2f(kv1.x * C2);
      e1.y = __builtin_amdgcn_exp2f(kv1.y * C2);
      e1.z = __builtin_amdgcn_exp2f(kv1.z * C2);
      e1.w = __builtin_amdgcn_exp2f(kv1.w * C2);
      *(float4*)&ekL[buf ^ 1][krow][kc8]     = e0;
      *(float4*)&ekL[buf ^ 1][krow][kc8 + 4] = e1;
    }

    __syncthreads();   // ONE barrier/tile: back buffers ready (incl. vmcnt drain)
    buf ^= 1;
  }

  // ---- epilogue: denominator reduce + 4-slice PV combine
  #pragma unroll
  for (int m = 1; m < 64; m <<= 1) dsum += __shfl_xor(dsum, m);
  if (lane == 0) lsum[w] = dsum;

  float* scr = &ekL[0][0][0];               // reuse: [8 rows][4 slices][64 d] = 8KB
  *(float4*)(scr + (size_t)(w * 4 + ks) * 64 + dq * 4) = acc;
  __syncthreads();

  if (t < 128) {
    const int r = t >> 4, d4 = t & 15;
    float4 o = make_float4(0.f, 0.f, 0.f, 0.f);
    #pragma unroll
    for (int s = 0; s < 4; ++s) {
      const float4 c = *(const float4*)(scr + (size_t)(r * 4 + s) * 64 + d4 * 4);
      o.x += c.x; o.y += c.y; o.z += c.z; o.w += c.w;
    }
    const float inv = 1.0f / lsum[r];
    o.x *= inv; o.y *= inv; o.z *= inv; o.w *= inv;
    *(float4*)(O + (size_t)(bb * LQ + q0 + r) * Dn + d4 * 4) = o;
  }
}
} // namespace

extern "C" void kernel_launch(void* const* d_in, const int* in_sizes, int n_in,
                              void* d_out, int out_size, void* d_ws, size_t ws_size,
                              hipStream_t stream) {
  (void)in_sizes; (void)n_in; (void)d_ws; (void)ws_size; (void)out_size;
  const float* Q = (const float*)d_in[0];
  const float* K = (const float*)d_in[1];
  const float* V = (const float*)d_in[2];
  float* O = (float*)d_out;
  addattn<<<dim3(Bn * (LQ / QT)), dim3(T), 0, stream>>>(Q, K, V, O);
}